// Round 2
// baseline (584.568 us; speedup 1.0000x reference)
//
#include <hip/hip_runtime.h>
#include <hip/hip_bf16.h>

typedef __bf16  bf16x8_t __attribute__((ext_vector_type(8)));
typedef float   f32x4_t  __attribute__((ext_vector_type(4)));
typedef short   s16x8_t  __attribute__((ext_vector_type(8)));

#define S_LEN    2048
#define HDIM     64
#define BQ       32
#define NTHREADS 1024
#define PSTR     2056   // P row stride in bf16 elems (pad 8 -> bank spread)
#define QSTR     72     // Q row stride in bf16 elems

__device__ __forceinline__ short f2bf(float f) {
    unsigned u = __builtin_bit_cast(unsigned, f);
    u += 0x7FFFu + ((u >> 16) & 1u);   // RNE
    return (short)(u >> 16);
}
__device__ __forceinline__ float bf2f(short s) {
    return __builtin_bit_cast(float, ((unsigned)(unsigned short)s) << 16);
}

// Detect the on-device mask dtype from its byte pattern (first 16 KB):
//   bool/int8 {0,1}:   nonzero bytes at all offsets mod 4     -> stride 1, off 0
//   int32 {0,1}:       nonzero only at offset 0 mod 4 (LE)    -> stride 4, off 0
//   float32 {0.,1.}:   nonzero only at offsets 2,3 (0x3F800000)-> stride 4, off 3
__global__ void detect_mask(const unsigned char* __restrict__ M, int* __restrict__ flags) {
    __shared__ int cnt[4];
    if (threadIdx.x < 4) cnt[threadIdx.x] = 0;
    __syncthreads();
    int local[4] = {0, 0, 0, 0};
    for (int i = threadIdx.x; i < 16384; i += 256)
        if (M[i]) local[i & 3]++;
    #pragma unroll
    for (int c = 0; c < 4; ++c)
        if (local[c]) atomicAdd(&cnt[c], local[c]);
    __syncthreads();
    if (threadIdx.x == 0) {
        int stride, off;
        if (cnt[1] == 0 && cnt[2] == 0 && cnt[3] == 0)      { stride = 4; off = 0; } // int32
        else if (cnt[0] == 0 && cnt[1] == 0)                { stride = 4; off = 3; } // float32
        else                                                { stride = 1; off = 0; } // bool/int8
        flags[0] = stride;
        flags[1] = off;
    }
}

__global__ __launch_bounds__(NTHREADS)
void sdpa_fused(const float* __restrict__ Q, const float* __restrict__ K,
                const float* __restrict__ V, const unsigned char* __restrict__ M,
                const int* __restrict__ MF, float* __restrict__ OUT)
{
    __shared__ short Plds[BQ * PSTR];   // 131584 B, unnormalized exp(score) in bf16
    __shared__ short Qlds[BQ * QSTR];   // 4608 B
    __shared__ float rowsum[BQ];

    const int tid  = threadIdx.x;
    const int wave = tid >> 6;
    const int lane = tid & 63;

    const int mstride = MF[0];
    const int moff    = MF[1];

    // XCD-friendly swizzle: 2048 blocks = 8 xcd * 256 slots; all 64 q-tiles of
    // one b land on one XCD so K[b]/V[b] (1 MB fp32) stay L2-resident.
    const int id   = blockIdx.x;
    const int slot = id >> 3;
    const int b    = ((slot >> 6) << 3) | (id & 7);   // 0..31
    const int q0   = (slot & 63) * BQ;                // 0..2016

    float* ctx_out  = OUT;                               // [32][2048][64]
    float* attn_out = OUT + (size_t)32 * S_LEN * HDIM;   // [32][2048][2048]

    // ---- Phase 0: Q tile -> LDS (bf16), zero rowsum
    {
        const int r  = tid >> 5;          // 0..31
        const int h2 = (tid & 31) * 2;    // 0..62
        const float2 qv = *(const float2*)(Q + ((size_t)b * S_LEN + q0 + r) * HDIM + h2);
        Qlds[r * QSTR + h2]     = f2bf(qv.x);
        Qlds[r * QSTR + h2 + 1] = f2bf(qv.y);
        if (tid < BQ) rowsum[tid] = 0.f;
    }
    __syncthreads();

    // ---- Q (A) fragments held in registers for whole score phase
    // mfma_f32_16x16x32_bf16 A layout: lane l -> A[l&15][(l>>4)*8 + e], e=0..7
    bf16x8_t afrag[2][2];
    {
        const int arow = lane & 15, akg = lane >> 4;
        #pragma unroll
        for (int m = 0; m < 2; ++m)
            #pragma unroll
            for (int kk = 0; kk < 2; ++kk)
                afrag[m][kk] = *(const bf16x8_t*)&Qlds[(m*16 + arow) * QSTR + kk*32 + akg*8];
    }

    // ---- Phase 1: scores = QK^T/8, mask, exp -> Plds (bf16); fp32 row sums
    float rsum[2][4] = {{0.f,0.f,0.f,0.f},{0.f,0.f,0.f,0.f}};
    {
        const float* Kb = K + (size_t)b * S_LEN * HDIM;
        const unsigned char* Mb = M
            + ((size_t)b * S_LEN * S_LEN + (size_t)q0 * S_LEN) * mstride + moff;
        const int col = lane & 15;
        const int kg  = lane >> 4;
        #pragma unroll 2
        for (int f = 0; f < 8; ++f) {
            const int n0 = wave * 128 + f * 16;   // 16 k-columns per fragment
            // B layout: lane l -> B[(l>>4)*8 + e][l&15] = K[n0 + (l&15)][h]
            const float* kp = Kb + (n0 + col) * HDIM + kg * 8;
            const float4 ka = *(const float4*)kp;
            const float4 kb = *(const float4*)(kp + 4);
            const float4 kc = *(const float4*)(kp + 32);
            const float4 kd = *(const float4*)(kp + 36);
            s16x8_t b0s, b1s;
            b0s[0]=f2bf(ka.x); b0s[1]=f2bf(ka.y); b0s[2]=f2bf(ka.z); b0s[3]=f2bf(ka.w);
            b0s[4]=f2bf(kb.x); b0s[5]=f2bf(kb.y); b0s[6]=f2bf(kb.z); b0s[7]=f2bf(kb.w);
            b1s[0]=f2bf(kc.x); b1s[1]=f2bf(kc.y); b1s[2]=f2bf(kc.z); b1s[3]=f2bf(kc.w);
            b1s[4]=f2bf(kd.x); b1s[5]=f2bf(kd.y); b1s[6]=f2bf(kd.z); b1s[7]=f2bf(kd.w);
            const bf16x8_t bf0 = __builtin_bit_cast(bf16x8_t, b0s);
            const bf16x8_t bf1 = __builtin_bit_cast(bf16x8_t, b1s);
            f32x4_t acc0 = {0.f,0.f,0.f,0.f}, acc1 = {0.f,0.f,0.f,0.f};
            acc0 = __builtin_amdgcn_mfma_f32_16x16x32_bf16(afrag[0][0], bf0, acc0, 0, 0, 0);
            acc0 = __builtin_amdgcn_mfma_f32_16x16x32_bf16(afrag[0][1], bf1, acc0, 0, 0, 0);
            acc1 = __builtin_amdgcn_mfma_f32_16x16x32_bf16(afrag[1][0], bf0, acc1, 0, 0, 0);
            acc1 = __builtin_amdgcn_mfma_f32_16x16x32_bf16(afrag[1][1], bf1, acc1, 0, 0, 0);
            // C/D layout (verified m89): col = lane&15, row = (lane>>4)*4 + reg
            #pragma unroll
            for (int m = 0; m < 2; ++m) {
                const f32x4_t a = m ? acc1 : acc0;
                #pragma unroll
                for (int r = 0; r < 4; ++r) {
                    const int row = m*16 + kg*4 + r;           // local q row
                    const unsigned char mk = Mb[(size_t)(row * S_LEN + n0 + col) * mstride];
                    const float p = mk ? 0.f : __expf(a[r] * 0.125f);
                    rsum[m][r] += p;
                    Plds[row * PSTR + n0 + col] = f2bf(p);
                }
            }
        }
    }

    // ---- rowsum reduction: across 16 lanes sharing a row, then across waves
    #pragma unroll
    for (int m = 0; m < 2; ++m)
        #pragma unroll
        for (int r = 0; r < 4; ++r) {
            float s = rsum[m][r];
            s += __shfl_xor(s, 1);
            s += __shfl_xor(s, 2);
            s += __shfl_xor(s, 4);
            s += __shfl_xor(s, 8);
            if ((lane & 15) == 0)
                atomicAdd(&rowsum[m*16 + (lane>>4)*4 + r], s);
        }
    __syncthreads();

    if (wave < 12) {
        // ---- attn write (HBM-bound): 768 threads stream 32x2048 fp32, vec8
        float* ab = attn_out + ((size_t)b * S_LEN + q0) * S_LEN;
        #pragma unroll 2
        for (int it = 0; it < 11; ++it) {
            const int flat = it * 768 + tid;     // vec8 chunk id
            if (flat < 8192) {
                const int row = flat >> 8;          // 0..31
                const int c0  = (flat & 255) * 8;   // 0..2040
                const float inv = 1.0f / rowsum[row];
                const s16x8_t pv = *(const s16x8_t*)&Plds[row * PSTR + c0];
                float4 o0, o1;
                o0.x = bf2f(pv[0]) * inv; o0.y = bf2f(pv[1]) * inv;
                o0.z = bf2f(pv[2]) * inv; o0.w = bf2f(pv[3]) * inv;
                o1.x = bf2f(pv[4]) * inv; o1.y = bf2f(pv[5]) * inv;
                o1.z = bf2f(pv[6]) * inv; o1.w = bf2f(pv[7]) * inv;
                float* op = ab + (size_t)row * S_LEN + c0;
                *(float4*)op       = o0;
                *(float4*)(op + 4) = o1;
            }
        }
    } else {
        // ---- PV (L2/MFMA-bound, overlaps the attn write): 4 waves,
        // each owns 16 ctx columns (V read exactly once per block), both
        // 16-row halves, full K=2048.
        const int hbase = (wave - 12) * 16;
        const float* Vb = V + (size_t)b * S_LEN * HDIM;
        const int col = lane & 15;
        const int kg  = lane >> 4;
        f32x4_t cacc0 = {0.f,0.f,0.f,0.f}, cacc1 = {0.f,0.f,0.f,0.f};
        for (int kc = 0; kc < 64; ++kc) {
            const int k0 = kc * 32;
            const bf16x8_t pa0 = *(const bf16x8_t*)&Plds[ col       * PSTR + k0 + kg*8];
            const bf16x8_t pa1 = *(const bf16x8_t*)&Plds[(16 + col) * PSTR + k0 + kg*8];
            // B layout: lane l -> V[k0 + (l>>4)*8 + e][hbase + (l&15)]
            const float* vp = Vb + (k0 + kg*8) * HDIM + hbase + col;
            s16x8_t vbs;
            #pragma unroll
            for (int e = 0; e < 8; ++e) vbs[e] = f2bf(vp[e * HDIM]);
            const bf16x8_t vb = __builtin_bit_cast(bf16x8_t, vbs);
            cacc0 = __builtin_amdgcn_mfma_f32_16x16x32_bf16(pa0, vb, cacc0, 0, 0, 0);
            cacc1 = __builtin_amdgcn_mfma_f32_16x16x32_bf16(pa1, vb, cacc1, 0, 0, 0);
        }
        #pragma unroll
        for (int r = 0; r < 4; ++r) {
            const int row0 = kg*4 + r;
            const int row1 = 16 + kg*4 + r;
            ctx_out[((size_t)b * S_LEN + q0 + row0) * HDIM + hbase + col] = cacc0[r] / rowsum[row0];
            ctx_out[((size_t)b * S_LEN + q0 + row1) * HDIM + hbase + col] = cacc1[r] / rowsum[row1];
        }
    }
}

extern "C" void kernel_launch(void* const* d_in, const int* in_sizes, int n_in,
                              void* d_out, int out_size, void* d_ws, size_t ws_size,
                              hipStream_t stream)
{
    const float* q = (const float*)d_in[0];
    const float* k = (const float*)d_in[1];
    const float* v = (const float*)d_in[2];
    const unsigned char* mask = (const unsigned char*)d_in[3];
    int* mflags = (int*)d_ws;
    float* out = (float*)d_out;
    detect_mask<<<dim3(1), dim3(256), 0, stream>>>(mask, mflags);
    sdpa_fused<<<dim3(2048), dim3(NTHREADS), 0, stream>>>(q, k, v, mask, mflags, out);
}

// Round 3
// 508.177 us; speedup vs baseline: 1.1503x; 1.1503x over previous
//
#include <hip/hip_runtime.h>
#include <hip/hip_bf16.h>

typedef __bf16  bf16x8_t __attribute__((ext_vector_type(8)));
typedef float   f32x4_t  __attribute__((ext_vector_type(4)));
typedef short   s16x8_t  __attribute__((ext_vector_type(8)));

#define S_LEN    2048
#define HDIM     64
#define BQ       16
#define NTHREADS 512
#define PSTR     2056   // P row stride in bf16 elems
#define QSTR     72     // Q row stride in bf16 elems

__device__ __forceinline__ short f2bf(float f) {
    return __builtin_bit_cast(short, (__bf16)f);   // native RNE cvt (1 op)
}
__device__ __forceinline__ float bf2f(short s) {
    return __builtin_bit_cast(float, ((unsigned)(unsigned short)s) << 16);
}

// Detect the on-device mask dtype from its byte pattern (first 16 KB):
//   bool/int8 {0,1}:   nonzero bytes at all offsets mod 4      -> stride 1
//   int32 {0,1}:       nonzero only at offset 0 mod 4 (LE)     -> stride 4
//   float32 {0.,1.}:   nonzero only at offsets 2,3 (0x3F800000)-> stride 4
__global__ void detect_mask(const unsigned char* __restrict__ M, int* __restrict__ flags) {
    __shared__ int cnt[4];
    if (threadIdx.x < 4) cnt[threadIdx.x] = 0;
    __syncthreads();
    int local[4] = {0, 0, 0, 0};
    for (int i = threadIdx.x; i < 16384; i += 256)
        if (M[i]) local[i & 3]++;
    #pragma unroll
    for (int c = 0; c < 4; ++c)
        if (local[c]) atomicAdd(&cnt[c], local[c]);
    __syncthreads();
    if (threadIdx.x == 0) {
        int stride;
        if (cnt[1] == 0 && cnt[2] == 0 && cnt[3] == 0)      stride = 4;  // int32
        else if (cnt[0] == 0 && cnt[1] == 0)                stride = 4;  // float32
        else                                                stride = 1;  // bool/int8
        flags[0] = stride;
    }
}

__global__ __launch_bounds__(NTHREADS, 4)
void sdpa_fused(const float* __restrict__ Q, const float* __restrict__ K,
                const float* __restrict__ V, const unsigned char* __restrict__ M,
                const int* __restrict__ MF, float* __restrict__ OUT)
{
    __shared__ short Plds[BQ * PSTR];   // 65792 B, exp(score) bf16, masked in phase 2a
    __shared__ short Qlds[BQ * QSTR];   // 2304 B
    __shared__ float rowsum[BQ];

    const int tid  = threadIdx.x;
    const int wave = tid >> 6;
    const int lane = tid & 63;
    const int col  = lane & 15;
    const int kg   = lane >> 4;

    const int mstride = MF[0];

    // 4096 blocks = 8 xcd * 512 slots; all 128 q-tiles of one b land on one XCD
    const int id   = blockIdx.x;
    const int slot = id >> 3;
    const int b    = ((slot >> 7) << 3) | (id & 7);   // 0..31
    const int q0   = (slot & 127) * BQ;               // 0..2032

    float* ctx_out  = OUT;                               // [32][2048][64]
    float* attn_out = OUT + (size_t)32 * S_LEN * HDIM;   // [32][2048][2048]

    // ---- Phase 0: Q tile -> LDS (bf16)
    {
        const int r  = tid >> 5;          // 0..15
        const int h2 = (tid & 31) * 2;    // 0..62
        const float2 qv = *(const float2*)(Q + ((size_t)b * S_LEN + q0 + r) * HDIM + h2);
        Qlds[r * QSTR + h2]     = f2bf(qv.x);
        Qlds[r * QSTR + h2 + 1] = f2bf(qv.y);
    }
    __syncthreads();

    // A-frag: lane l -> A[l&15][(l>>4)*8 + e]
    bf16x8_t afrag[2];
    #pragma unroll
    for (int kk = 0; kk < 2; ++kk)
        afrag[kk] = *(const bf16x8_t*)&Qlds[col * QSTR + kk * 32 + kg * 8];

    // ---- Phase 1: scores = QK^T/8, exp -> Plds (bf16). NO mask here.
    {
        const float* Kb = K + (size_t)b * S_LEN * HDIM;
        #pragma unroll 2
        for (int f = 0; f < 16; ++f) {
            const int n0 = wave * 256 + f * 16;
            const float* kp = Kb + (n0 + col) * HDIM + kg * 8;
            const float4 ka = *(const float4*)kp;
            const float4 kb = *(const float4*)(kp + 4);
            const float4 kc = *(const float4*)(kp + 32);
            const float4 kd = *(const float4*)(kp + 36);
            s16x8_t b0s, b1s;
            b0s[0]=f2bf(ka.x); b0s[1]=f2bf(ka.y); b0s[2]=f2bf(ka.z); b0s[3]=f2bf(ka.w);
            b0s[4]=f2bf(kb.x); b0s[5]=f2bf(kb.y); b0s[6]=f2bf(kb.z); b0s[7]=f2bf(kb.w);
            b1s[0]=f2bf(kc.x); b1s[1]=f2bf(kc.y); b1s[2]=f2bf(kc.z); b1s[3]=f2bf(kc.w);
            b1s[4]=f2bf(kd.x); b1s[5]=f2bf(kd.y); b1s[6]=f2bf(kd.z); b1s[7]=f2bf(kd.w);
            f32x4_t acc = {0.f, 0.f, 0.f, 0.f};
            acc = __builtin_amdgcn_mfma_f32_16x16x32_bf16(afrag[0], __builtin_bit_cast(bf16x8_t, b0s), acc, 0, 0, 0);
            acc = __builtin_amdgcn_mfma_f32_16x16x32_bf16(afrag[1], __builtin_bit_cast(bf16x8_t, b1s), acc, 0, 0, 0);
            // C/D: col = lane&15, row = (lane>>4)*4 + reg
            #pragma unroll
            for (int r = 0; r < 4; ++r)
                Plds[(kg*4 + r) * PSTR + n0 + col] = f2bf(__expf(acc[r] * 0.125f));
        }
    }
    __syncthreads();

    // ---- Phase 2a: coalesced mask apply (zero P in LDS) + rowsum from bf16 P
    {
        const int row = tid >> 5;        // 0..15
        const int lr  = tid & 31;
        float s = 0.f;
        if (mstride == 1) {
            const unsigned char* mrow = M + (size_t)b * S_LEN * S_LEN + (size_t)(q0 + row) * S_LEN;
            #pragma unroll 2
            for (int i = 0; i < 8; ++i) {
                const int c0 = (lr + 32 * i) * 8;
                s16x8_t pv = *(s16x8_t*)&Plds[row * PSTR + c0];
                const uint2 mm = *(const uint2*)(mrow + c0);
                #pragma unroll
                for (int e = 0; e < 4; ++e) {
                    if ((mm.x >> (8*e)) & 0xFFu) pv[e] = 0; else s += bf2f(pv[e]);
                    if ((mm.y >> (8*e)) & 0xFFu) pv[4+e] = 0; else s += bf2f(pv[4+e]);
                }
                *(s16x8_t*)&Plds[row * PSTR + c0] = pv;
            }
        } else {
            const unsigned* mrow = (const unsigned*)M + (size_t)b * S_LEN * S_LEN + (size_t)(q0 + row) * S_LEN;
            #pragma unroll 2
            for (int i = 0; i < 8; ++i) {
                const int c0 = (lr + 32 * i) * 8;
                s16x8_t pv = *(s16x8_t*)&Plds[row * PSTR + c0];
                const uint4 w0 = *(const uint4*)(mrow + c0);
                const uint4 w1 = *(const uint4*)(mrow + c0 + 4);
                if (w0.x) pv[0] = 0; else s += bf2f(pv[0]);
                if (w0.y) pv[1] = 0; else s += bf2f(pv[1]);
                if (w0.z) pv[2] = 0; else s += bf2f(pv[2]);
                if (w0.w) pv[3] = 0; else s += bf2f(pv[3]);
                if (w1.x) pv[4] = 0; else s += bf2f(pv[4]);
                if (w1.y) pv[5] = 0; else s += bf2f(pv[5]);
                if (w1.z) pv[6] = 0; else s += bf2f(pv[6]);
                if (w1.w) pv[7] = 0; else s += bf2f(pv[7]);
                *(s16x8_t*)&Plds[row * PSTR + c0] = pv;
            }
        }
        s += __shfl_xor(s, 1);
        s += __shfl_xor(s, 2);
        s += __shfl_xor(s, 4);
        s += __shfl_xor(s, 8);
        s += __shfl_xor(s, 16);
        if (lr == 0) rowsum[row] = s;
    }
    __syncthreads();

    if (wave < 4) {
        // ---- Phase 2b: attn write (HBM-bound): 256 threads, 16 rows x 256 vec8 chunks
        float* ab = attn_out + ((size_t)b * S_LEN + q0) * S_LEN;
        #pragma unroll 2
        for (int it = 0; it < 16; ++it) {
            const int flat = it * 256 + tid;    // 0..4095
            const int row  = flat >> 8;
            const int c0   = (flat & 255) * 8;
            const float inv = 1.0f / rowsum[row];
            const s16x8_t pv = *(const s16x8_t*)&Plds[row * PSTR + c0];
            float4 o0, o1;
            o0.x = bf2f(pv[0]) * inv; o0.y = bf2f(pv[1]) * inv;
            o0.z = bf2f(pv[2]) * inv; o0.w = bf2f(pv[3]) * inv;
            o1.x = bf2f(pv[4]) * inv; o1.y = bf2f(pv[5]) * inv;
            o1.z = bf2f(pv[6]) * inv; o1.w = bf2f(pv[7]) * inv;
            float* op = ab + (size_t)row * S_LEN + c0;
            *(float4*)op       = o0;
            *(float4*)(op + 4) = o1;
        }
    } else {
        // ---- Phase 2c: PV. 4 waves, each owns 16 ctx cols; V in registers
        // with distance-2 prefetch (static indexing only).
        const int hbase = (wave - 4) * 16;
        const float* Vb = V + (size_t)b * S_LEN * HDIM + hbase + col;

        float p0[8], p1[8];
        #define LOADV(k0, dst)                                          \
            { const float* vp = Vb + (size_t)((k0) + kg * 8) * HDIM;    \
              dst[0] = vp[0*HDIM]; dst[1] = vp[1*HDIM];                 \
              dst[2] = vp[2*HDIM]; dst[3] = vp[3*HDIM];                 \
              dst[4] = vp[4*HDIM]; dst[5] = vp[5*HDIM];                 \
              dst[6] = vp[6*HDIM]; dst[7] = vp[7*HDIM]; }
        #define PACK(src, dst)                                          \
            { s16x8_t t;                                                \
              t[0]=f2bf(src[0]); t[1]=f2bf(src[1]); t[2]=f2bf(src[2]);  \
              t[3]=f2bf(src[3]); t[4]=f2bf(src[4]); t[5]=f2bf(src[5]);  \
              t[6]=f2bf(src[6]); t[7]=f2bf(src[7]);                     \
              dst = __builtin_bit_cast(bf16x8_t, t); }

        LOADV(0,  p0);
        LOADV(32, p1);
        f32x4_t cacc = {0.f, 0.f, 0.f, 0.f};
        for (int kc2 = 0; kc2 < 32; ++kc2) {
            const int ke = kc2 * 2;
            // even chunk ke (regs p0)
            {
                const bf16x8_t pa = *(const bf16x8_t*)&Plds[col * PSTR + ke*32 + kg*8];
                bf16x8_t vbf; PACK(p0, vbf);
                if (ke + 2 < 64) LOADV((ke + 2) * 32, p0);
                cacc = __builtin_amdgcn_mfma_f32_16x16x32_bf16(pa, vbf, cacc, 0, 0, 0);
            }
            // odd chunk ke+1 (regs p1)
            {
                const bf16x8_t pa = *(const bf16x8_t*)&Plds[col * PSTR + (ke+1)*32 + kg*8];
                bf16x8_t vbf; PACK(p1, vbf);
                if (ke + 3 < 64) LOADV((ke + 3) * 32, p1);
                cacc = __builtin_amdgcn_mfma_f32_16x16x32_bf16(pa, vbf, cacc, 0, 0, 0);
            }
        }
        #undef LOADV
        #undef PACK
        // D: col = lane&15 (=ctx col), row = kg*4 + reg (=q row)
        #pragma unroll
        for (int r = 0; r < 4; ++r) {
            const int row = kg * 4 + r;
            ctx_out[((size_t)b * S_LEN + q0 + row) * HDIM + hbase + col] = cacc[r] / rowsum[row];
        }
    }
}

extern "C" void kernel_launch(void* const* d_in, const int* in_sizes, int n_in,
                              void* d_out, int out_size, void* d_ws, size_t ws_size,
                              hipStream_t stream)
{
    const float* q = (const float*)d_in[0];
    const float* k = (const float*)d_in[1];
    const float* v = (const float*)d_in[2];
    const unsigned char* mask = (const unsigned char*)d_in[3];
    int* mflags = (int*)d_ws;
    float* out = (float*)d_out;
    detect_mask<<<dim3(1), dim3(256), 0, stream>>>(mask, mflags);
    sdpa_fused<<<dim3(4096), dim3(NTHREADS), 0, stream>>>(q, k, v, mask, mflags, out);
}